// Round 14
// baseline (241.640 us; speedup 1.0000x reference)
//
#include <hip/hip_runtime.h>

#define BATCH 16
#define CH    64
#define TLEN  200
#define NP    30
#define HID   128
#define NSEQ  (BATCH * NP)   // 480
#define HP    144            // hz (f16) row pitch in halves (288 B)
#define H8P   160            // hz8 (fp8) row pitch in bytes
#define XP    72             // xlds row pitch in halves (144 B)
#define XGW   520            // xgb row pitch in floats (2080 B)

typedef _Float16 half8 __attribute__((ext_vector_type(8)));
typedef float    f32x4 __attribute__((ext_vector_type(4)));
typedef int      i32x8 __attribute__((ext_vector_type(8)));
typedef unsigned char u8;

__device__ __forceinline__ float sigm_fast(float x) {
    return __builtin_amdgcn_rcpf(1.0f + __expf(-x));
}
__device__ __forceinline__ float tanh_fast(float x) {
    return 1.0f - 2.0f * __builtin_amdgcn_rcpf(__expf(2.0f * x) + 1.0f);
}
__device__ __forceinline__ half8 cvt8(float4 a, float4 b) {
    return (half8){(_Float16)a.x,(_Float16)a.y,(_Float16)a.z,(_Float16)a.w,
                   (_Float16)b.x,(_Float16)b.y,(_Float16)b.z,(_Float16)b.w};
}

#define MFMA16(A,B,C) __builtin_amdgcn_mfma_f32_16x16x32_f16((A),(B),(C),0,0,0)
// fmt 0 = fp8 e4m3 (OCP), e8m0 scale 127 = x1.0
#define MFMA8(A,B,C) __builtin_amdgcn_mfma_scale_f32_16x16x128_f8f6f4((A),(B),(C),0,0,0,127,0,127)

// ---------------------------------------------------------------------------
// Fused LSTM. r14: break the barrier phase-lock. 480 blocks x 256 threads
// (4 waves), ONE sequence per block, ~63 KB LDS -> TWO independent blocks
// co-resident per CU. The 2 waves/SIMD now come from DIFFERENT blocks with
// independent barriers: when one block stalls (post-barrier ds_read latency,
// MFMA latency, serial act chain, barrier wait — the ~720 cy/step both-pipes-
// idle bucket r13 exposed), the other block's waves issue. r3-r13 were all
// latency-bound with every wave phase-locked on the same barrier.
//   - wave w owns hid cols {32w+16ct+lr, ct=0,1} x 4 gate types.
//   - i,f,o gates: fp8-e4m3 K=128 scaled MFMA (validated r13, absmax 0.0039);
//     g stays f16. h dual-stored f16+fp8, replicated rows {0,1}/{2,3} so C
//     reg 0 of lanes 0-31 IS the lane's cell (ct = lq); row 4 = shared zero.
//   - x LDS-resident (28.8 KB); xg per-8-step burst (f16, bias folded).
// ---------------------------------------------------------------------------
__global__ __launch_bounds__(256, 2) void fused_lstm(
    const float* __restrict__ x, const float* __restrict__ W_ih,
    const float* __restrict__ W_hh, const float* __restrict__ b_ih,
    const float* __restrict__ b_hh, const float* __restrict__ W_fc,
    const float* __restrict__ b_fc, float* __restrict__ out)
{
    const int tid = threadIdx.x;
    const int w  = tid >> 6;     // wave 0..3 -> owns hid [32w, 32w+32)
    const int l  = tid & 63;
    const int lr = l & 15;
    const int lq = l >> 4;

    // XCD-chunked swizzle: XCD c gets seqs c*60..c*60+59 (= 2 full batches)
    const int blk = blockIdx.x;
    const int n   = (blk & 7) * 60 + (blk >> 3);   // 480 % 8 == 0 -> bijective
    const int b0  = n / NP;
    const int p0  = n % NP;

    __shared__ __align__(16) _Float16 hz[5][HP];    // rows {0,1}=buf0 (h,replica),{2,3}=buf1,{4}=zero
    __shared__ __align__(16) u8       hz8[5][H8P];  // fp8 h, same scheme
    __shared__ __align__(16) _Float16 xlds[TLEN][XP];   // 28.8 KB, this seq's x
    __shared__ __align__(16) float    xgb[2][8][XGW];   // 33.3 KB, xg+bias (f32), row=step

    // ---- W fragments in registers (loaded once) ----
    i32x8 b8[3][2];      // fp8 W_hh for {i,f,o} x col-tile ct
    {
        const int Ts[3] = {0, 1, 3};
#pragma unroll
        for (int q = 0; q < 3; ++q)
#pragma unroll
          for (int ct = 0; ct < 2; ++ct) {
            const float* rw = W_hh + (size_t)(128*Ts[q] + 32*w + 16*ct + lr) * HID + 32*lq;
            i32x8 pk;
#pragma unroll
            for (int r = 0; r < 8; ++r) {
                int v = __builtin_amdgcn_cvt_pk_fp8_f32(rw[4*r],     rw[4*r + 1], 0, false);
                v     = __builtin_amdgcn_cvt_pk_fp8_f32(rw[4*r + 2], rw[4*r + 3], v, true);
                pk[r] = v;
            }
            b8[q][ct] = pk;
          }
    }
    half8 bg16[2][4];    // f16 W_hh for g-gate, col-tile x K-chunk
#pragma unroll
    for (int ct = 0; ct < 2; ++ct) {
        const float* rh = W_hh + (size_t)(256 + 32*w + 16*ct + lr) * HID;
#pragma unroll
        for (int kt = 0; kt < 4; ++kt) {
            const int k0 = 32*kt + 8*lq;
            bg16[ct][kt] = cvt8(*(const float4*)(rh + k0), *(const float4*)(rh + k0 + 4));
        }
    }
    half8 bih[4][2][2];  // f16 W_ih, gate x col-tile x K-chunk (K=64)
    float biasx[4][2];
#pragma unroll
    for (int T = 0; T < 4; ++T)
#pragma unroll
      for (int ct = 0; ct < 2; ++ct) {
        const int g = 128*T + 32*w + 16*ct + lr;
        const float* ri = W_ih + (size_t)g * CH;
#pragma unroll
        for (int j = 0; j < 2; ++j) {
            const int k0 = 32*j + 8*lq;
            bih[T][ct][j] = cvt8(*(const float4*)(ri + k0), *(const float4*)(ri + k0 + 4));
        }
        biasx[T][ct] = b_ih[g] + b_hh[g];
      }

    // zero h buffers (rows 0-3 = h_0 = 0; row 4 = permanent zero row)
    if (tid < (5 * HP) / 2) ((unsigned*)hz)[tid] = 0u;
    if (tid < (5 * H8P) / 4) ((unsigned*)hz8)[tid] = 0u;

    // ---- prologue: stage this seq's x into LDS (one-time gather)
    for (int e = tid; e < CH * TLEN; e += 256) {
        const int t = e % TLEN, c = e / TLEN;
        xlds[t][c] = (_Float16)x[((size_t)(b0 * CH + c) * TLEN + t) * NP + p0];
    }
    float cst = 0.f;                        // c-state: valid in lanes l<32
    const int ct1 = lq & 1;                 // lane's col-tile (lanes 0-31)
    const int hid = 32*w + 16*ct1 + lr;     // lane's cell
    // A-frag source rows: lr==0 -> primary, lr==4 -> replica, else ZERO row
    const int r0 = (lr == 0) ? 0 : (lr == 4) ? 1 : 4;   // buf 0
    const int r1 = (lr == 0) ? 2 : (lr == 4) ? 3 : 4;   // buf 1
    const _Float16* hpA  = &hz[r0][8 * lq];
    const _Float16* hpB  = &hz[r1][8 * lq];
    const u8*       hp8A = &hz8[r0][32 * lq];
    const u8*       hp8B = &hz8[r1][32 * lq];
    __syncthreads();                        // h buffers + xlds resident

    // per-period xg GEMM: x-tile rows (lr&7) = step offset; C rows 8-15 dup/dead.
#define XG_BURST(P, TB) {                                                         \
        const _Float16* xr_ = &xlds[8*(P) + (lr & 7)][8*lq];                      \
        half8 xf0_ = *(const half8*)xr_;                                          \
        half8 xf1_ = *(const half8*)(xr_ + 32);                                   \
        f32x4 ac_[4][2];                                                          \
        _Pragma("unroll") for (int T_ = 0; T_ < 4; ++T_)                          \
        { _Pragma("unroll") for (int c_ = 0; c_ < 2; ++c_) {                      \
            f32x4 a_ = {biasx[T_][c_], biasx[T_][c_], biasx[T_][c_], biasx[T_][c_]}; \
            a_ = MFMA16(xf0_, bih[T_][c_][0], a_);                                \
            a_ = MFMA16(xf1_, bih[T_][c_][1], a_);                                \
            ac_[T_][c_] = a_;                                                     \
        } }                                                                       \
        if (lq < 2) {                                                             \
            _Pragma("unroll") for (int c_ = 0; c_ < 2; ++c_)                      \
            { _Pragma("unroll") for (int r_ = 0; r_ < 4; ++r_) {                  \
                float* dst_ = &xgb[TB][4*lq + r_][(32*w + 16*c_ + lr) * 4];       \
                *(f32x4*)dst_ = (f32x4){ac_[0][c_][r_], ac_[1][c_][r_],           \
                                        ac_[2][c_][r_], ac_[3][c_][r_]};          \
            } }                                                                   \
        } }

    XG_BURST(0, 0)          // xg for period 0
    __syncthreads();

#pragma unroll 1
    for (int p = 0; p < 25; ++p) {
        const int pe = p & 1;
#pragma unroll
        for (int k = 0; k < 8; ++k) {
            const int cur = k & 1;       // t = 8p+k, t&1 = k&1
            const int nxt = cur ^ 1;
            // lane's 4 gate xg values (f32 quad; lanes 32-63 duplicate = broadcast)
            f32x4 xg4 = *(const f32x4*)&xgb[pe][k][hid * 4];
            // A fragments: fp8 (32 B) for i,f,o; f16 chunks for g
            i32x8 a8 = *(const i32x8*)(cur ? hp8B : hp8A);
            const _Float16* hr = cur ? hpB : hpA;
            half8 a0 = *(const half8*)(hr);
            half8 a1 = *(const half8*)(hr + 32);
            half8 a2 = *(const half8*)(hr + 64);
            half8 a3 = *(const half8*)(hr + 96);
            f32x4 zz = {0.f, 0.f, 0.f, 0.f};
            __builtin_amdgcn_s_setprio(1);
            // i,f: one K=128 fp8 MFMA per col-tile; g: f16 chains — EARLY
            f32x4 ci0 = MFMA8(a8, b8[0][0], zz);
            f32x4 ci1 = MFMA8(a8, b8[0][1], zz);
            f32x4 cf0 = MFMA8(a8, b8[1][0], zz);
            f32x4 cf1 = MFMA8(a8, b8[1][1], zz);
            f32x4 cg0 = MFMA16(a0, bg16[0][0], zz);
            cg0 = MFMA16(a1, bg16[0][1], cg0);
            cg0 = MFMA16(a2, bg16[0][2], cg0);
            cg0 = MFMA16(a3, bg16[0][3], cg0);
            f32x4 cg1 = MFMA16(a0, bg16[1][0], zz);
            cg1 = MFMA16(a1, bg16[1][1], cg1);
            cg1 = MFMA16(a2, bg16[1][2], cg1);
            cg1 = MFMA16(a3, bg16[1][3], cg1);
            // early act front (reg 0 row 4*lq: rows 0,4 = h-replicas -> lanes
            // 0-31 own cell (hid, ct=lq); lanes 32-63 garbage, writes masked)
            float gi = (ct1 ? ci1[0] : ci0[0]) + xg4[0];
            float gf = (ct1 ? cf1[0] : cf0[0]) + xg4[1];
            float gg = (ct1 ? cg1[0] : cg0[0]) + xg4[2];
            float si = sigm_fast(gi);
            float sf = sigm_fast(gf);
            float tg = tanh_fast(gg);
            float cnew = sf * cst + si * tg;
            // o-gate LAST
            f32x4 co0 = MFMA8(a8, b8[2][0], zz);
            f32x4 co1 = MFMA8(a8, b8[2][1], zz);
            __builtin_amdgcn_s_setprio(0);
            if (k == 0 && p < 24) XG_BURST(p + 1, pe ^ 1)    // xg for period p+1
            // tail: sigm(go) || tanh(c) -> mul -> cvt -> writes (f16+fp8 x2 rows)
            float hv = sigm_fast((ct1 ? co1[0] : co0[0]) + xg4[3]) * tanh_fast(cnew);
            cst = cnew;
            if (l < 32) {
                _Float16 hh = (_Float16)hv;
                hz[2*nxt][hid]     = hh;
                hz[2*nxt + 1][hid] = hh;     // replica row (feeds A row 4)
                u8 hb = (u8)__builtin_amdgcn_cvt_pk_fp8_f32(hv, hv, 0, false);
                hz8[2*nxt][hid]     = hb;
                hz8[2*nxt + 1][hid] = hb;
            }
            __syncthreads();
        }
    }

    // FC epilogue: h_200 in hz row 0 (t=199 wrote nxt=0)
    if (tid < CH) {
        const int ch = tid;
        const float* wf = W_fc + (size_t)ch * HID;
        float acc = b_fc[ch];
#pragma unroll
        for (int j8 = 0; j8 < 16; ++j8) {
            half8 hv = *(const half8*)&hz[0][8 * j8];
            float4 w0 = *(const float4*)(wf + 8 * j8);
            float4 w1 = *(const float4*)(wf + 8 * j8 + 4);
            acc += w0.x * (float)hv[0] + w0.y * (float)hv[1]
                 + w0.z * (float)hv[2] + w0.w * (float)hv[3]
                 + w1.x * (float)hv[4] + w1.y * (float)hv[5]
                 + w1.z * (float)hv[6] + w1.w * (float)hv[7];
        }
        out[(size_t)n * CH + ch] = acc;
    }
}

extern "C" void kernel_launch(void* const* d_in, const int* in_sizes, int n_in,
                              void* d_out, int out_size, void* d_ws, size_t ws_size,
                              hipStream_t stream) {
    (void)in_sizes; (void)n_in; (void)out_size; (void)d_ws; (void)ws_size;
    fused_lstm<<<NSEQ, 256, 0, stream>>>(
        (const float*)d_in[0], (const float*)d_in[1], (const float*)d_in[2],
        (const float*)d_in[3], (const float*)d_in[4], (const float*)d_in[5],
        (const float*)d_in[6], (float*)d_out);
}